// Round 1
// baseline (53.656 us; speedup 1.0000x reference)
//
#include <hip/hip_runtime.h>
#include <hip/hip_bf16.h>
#include <math.h>

#define HIDDEN 2048
#define NH 16
#define NKV 2
#define HD 128
#define CTX 4096
#define NL 36
#define EPS 1e-6f

#define CHUNK 128
#define NCHUNKS (CTX / CHUNK)   /* 32 */
#define HPB 2                   /* Q heads per attn block */
#define NPAIR (NH / HPB)        /* 8 */

/* ws layout (float offsets) */
#define WS_QRAW 0
#define WS_KRAW 2048
#define WS_VRAW 2304
#define WS_PART 2560
#define PART_STRIDE 130
#define WS_CTX (WS_PART + NH * NCHUNKS * PART_STRIDE)  /* 2560 + 66560 = 69120 */

#define RSQRT_HD 0.08838834764831845f  /* 1/sqrt(128) */

// ---------------------------------------------------------------- K1: QKV
__global__ __launch_bounds__(256) void qkv_kernel(
    const float* __restrict__ x, const float* __restrict__ lnw,
    const float* __restrict__ wq, const float* __restrict__ bq,
    const float* __restrict__ wk, const float* __restrict__ bk,
    const float* __restrict__ wv, const float* __restrict__ bv,
    float* __restrict__ ws)
{
    __shared__ float nx[HIDDEN];
    __shared__ float red[4];
    const int t = threadIdx.x;
    const int lane = t & 63, wid = t >> 6;

    // RMSNorm (redundant per block; x/lnw are 8KB each, L2/L3-cached)
    float4 xa = ((const float4*)x)[t * 2];
    float4 xb = ((const float4*)x)[t * 2 + 1];
    float ss = xa.x*xa.x + xa.y*xa.y + xa.z*xa.z + xa.w*xa.w
             + xb.x*xb.x + xb.y*xb.y + xb.z*xb.z + xb.w*xb.w;
    #pragma unroll
    for (int m = 32; m; m >>= 1) ss += __shfl_xor(ss, m);
    if (lane == 0) red[wid] = ss;
    __syncthreads();
    float inv = rsqrtf((red[0] + red[1] + red[2] + red[3]) / (float)HIDDEN + EPS);
    float4 la = ((const float4*)lnw)[t * 2];
    float4 lb = ((const float4*)lnw)[t * 2 + 1];
    float4 na, nb;
    na.x = xa.x * inv * la.x; na.y = xa.y * inv * la.y;
    na.z = xa.z * inv * la.z; na.w = xa.w * inv * la.w;
    nb.x = xb.x * inv * lb.x; nb.y = xb.y * inv * lb.y;
    nb.z = xb.z * inv * lb.z; nb.w = xb.w * inv * lb.w;
    ((float4*)nx)[t * 2] = na;
    ((float4*)nx)[t * 2 + 1] = nb;
    __syncthreads();

    // 8 rows per block, 2 per wave. Global row R in [0, 2560)
    const int R0 = blockIdx.x * 8 + wid * 2;

    const float *w0, *w1;
    float b0, b1;
    float *dst0, *dst1;
    {
        int R = R0;
        if (R < 2048)      { w0 = wq + (size_t)R * HIDDEN;          b0 = bq[R];        dst0 = ws + WS_QRAW + R; }
        else if (R < 2304) { int r = R - 2048; w0 = wk + (size_t)r * HIDDEN; b0 = bk[r]; dst0 = ws + WS_KRAW + r; }
        else               { int r = R - 2304; w0 = wv + (size_t)r * HIDDEN; b0 = bv[r]; dst0 = ws + WS_VRAW + r; }
        R = R0 + 1;
        if (R < 2048)      { w1 = wq + (size_t)R * HIDDEN;          b1 = bq[R];        dst1 = ws + WS_QRAW + R; }
        else if (R < 2304) { int r = R - 2048; w1 = wk + (size_t)r * HIDDEN; b1 = bk[r]; dst1 = ws + WS_KRAW + r; }
        else               { int r = R - 2304; w1 = wv + (size_t)r * HIDDEN; b1 = bv[r]; dst1 = ws + WS_VRAW + r; }
    }

    const float4* w04 = (const float4*)w0;
    const float4* w14 = (const float4*)w1;
    const float4* nx4 = (const float4*)nx;
    float a0 = 0.f, a1 = 0.f;
    #pragma unroll
    for (int j = 0; j < 8; ++j) {
        float4 n = nx4[j * 64 + lane];
        float4 u = w04[j * 64 + lane];
        float4 v = w14[j * 64 + lane];
        a0 += u.x*n.x + u.y*n.y + u.z*n.z + u.w*n.w;
        a1 += v.x*n.x + v.y*n.y + v.z*n.z + v.w*n.w;
    }
    #pragma unroll
    for (int m = 32; m; m >>= 1) { a0 += __shfl_xor(a0, m); a1 += __shfl_xor(a1, m); }
    if (lane == 0) { *dst0 = a0 + b0; *dst1 = a1 + b1; }
}

// ------------------------------------------------------- K2: attn partials
__global__ __launch_bounds__(256) void attn_kernel(
    const float* __restrict__ kv, const int* __restrict__ curpos,
    float* __restrict__ ws)
{
    const int pos = curpos[0];
    const int pairIdx = blockIdx.x / NCHUNKS;
    const int c = blockIdx.x % NCHUNKS;
    const int start = c * CHUNK;
    if (start > pos) return;
    const int nvalid = min(CHUNK, pos + 1 - start);
    const int h0 = pairIdx * HPB;
    const int kvh = h0 / (NH / NKV);
    const float* kc = kv + (size_t)kvh * CTX * HD;
    const float* vc = kv + (size_t)NL * NKV * CTX * HD + (size_t)kvh * CTX * HD;

    __shared__ float cc[64], sn[64];
    __shared__ float qr[HPB][HD];
    __shared__ float sc[HPB][CHUNK];
    __shared__ float ml[HPB][2];
    __shared__ float ctxh[HPB][HD];

    const int t = threadIdx.x;
    const int lane = t & 63, wid = t >> 6;

    if (t < 64) {
        double e = (double)t / 64.0;
        double a = (double)pos * pow(1000000.0, -e);
        cc[t] = (float)cos(a);
        sn[t] = (float)sin(a);
    }
    __syncthreads();

    if (t < HPB * HD) {
        int hh = t >> 7, d = t & 127;
        const float* q = ws + WS_QRAW + (size_t)(h0 + hh) * HD;
        float qv = q[d], qp = q[d ^ 64];
        float r = (d < 64) ? -qp : qp;
        qr[hh][d] = (qv * cc[d & 63] + r * sn[d & 63]) * RSQRT_HD;
    }
    __syncthreads();

    // scores: 16 groups of 16 lanes; each group one position per iter
    const int grp = t >> 4, li = t & 15;
    for (int base = 0; base < nvalid; base += 16) {
        const int pl = base + grp;
        float s0 = 0.f, s1 = 0.f;
        if (pl < nvalid) {
            const int p = start + pl;
            float kd[8];
            if (p == pos) {  // fresh k, roped on the fly
                const float* kr = ws + WS_KRAW + (size_t)kvh * HD;
                #pragma unroll
                for (int j = 0; j < 8; ++j) {
                    int d = li * 8 + j;
                    float kvd = kr[d], kp = kr[d ^ 64];
                    float r = (d < 64) ? -kp : kp;
                    kd[j] = kvd * cc[d & 63] + r * sn[d & 63];
                }
            } else {
                const float4* kp4 = (const float4*)(kc + (size_t)p * HD + li * 8);
                float4 ka = kp4[0], kb = kp4[1];
                kd[0]=ka.x; kd[1]=ka.y; kd[2]=ka.z; kd[3]=ka.w;
                kd[4]=kb.x; kd[5]=kb.y; kd[6]=kb.z; kd[7]=kb.w;
            }
            #pragma unroll
            for (int j = 0; j < 8; ++j) {
                int d = li * 8 + j;
                s0 += qr[0][d] * kd[j];
                s1 += qr[1][d] * kd[j];
            }
        }
        #pragma unroll
        for (int m = 1; m < 16; m <<= 1) { s0 += __shfl_xor(s0, m); s1 += __shfl_xor(s1, m); }
        if (pl < nvalid && li == 0) { sc[0][pl] = s0; sc[1][pl] = s1; }
    }
    __syncthreads();

    // per-head softmax stats: wave 0 -> head 0, wave 1 -> head 1
    if (wid < HPB) {
        float m = -INFINITY;
        for (int p = lane; p < nvalid; p += 64) m = fmaxf(m, sc[wid][p]);
        #pragma unroll
        for (int mm = 32; mm; mm >>= 1) m = fmaxf(m, __shfl_xor(m, mm));
        float l = 0.f;
        for (int p = lane; p < nvalid; p += 64) {
            float e = expf(sc[wid][p] - m);
            sc[wid][p] = e;
            l += e;
        }
        #pragma unroll
        for (int mm = 32; mm; mm >>= 1) l += __shfl_xor(l, mm);
        if (lane == 0) { ml[wid][0] = m; ml[wid][1] = l; }
    }
    __syncthreads();

    // ctx partial: thread owns one dim, two position streams
    const int d = t & 127, half = t >> 7;
    float a0 = 0.f, a1 = 0.f;
    for (int pl = half; pl < nvalid; pl += 2) {
        const int p = start + pl;
        const float* vp = (p == pos) ? (ws + WS_VRAW + (size_t)kvh * HD)
                                     : (vc + (size_t)p * HD);
        float v = vp[d];
        a0 += sc[0][pl] * v;
        a1 += sc[1][pl] * v;
    }
    if (half == 0) { ctxh[0][d] = a0; ctxh[1][d] = a1; }
    __syncthreads();
    if (half == 1) { ctxh[0][d] += a0; ctxh[1][d] += a1; }
    __syncthreads();

    if (t < HPB * HD) {
        int hh = t >> 7, dd = t & 127;
        float* part = ws + WS_PART + ((size_t)(h0 + hh) * NCHUNKS + c) * PART_STRIDE;
        part[2 + dd] = ctxh[hh][dd];
        if (dd == 0) { part[0] = ml[hh][0]; part[1] = ml[hh][1]; }
    }
}

// ---------------------------------------------------------- K3: combine
__global__ __launch_bounds__(128) void combine_kernel(
    const int* __restrict__ curpos, float* __restrict__ ws)
{
    const int pos = curpos[0];
    const int h = blockIdx.x;
    const int d = threadIdx.x;
    const int nc = pos / CHUNK + 1;
    float M = -INFINITY;
    for (int c = 0; c < nc; ++c)
        M = fmaxf(M, ws[WS_PART + ((size_t)h * NCHUNKS + c) * PART_STRIDE]);
    float L = 0.f, acc = 0.f;
    for (int c = 0; c < nc; ++c) {
        const float* part = ws + WS_PART + ((size_t)h * NCHUNKS + c) * PART_STRIDE;
        float w = expf(part[0] - M);
        L += w * part[1];
        acc += w * part[2 + d];
    }
    ws[WS_CTX + h * HD + d] = acc / L;
}

// ----------------------------------------------- K4: out proj + residual
__global__ __launch_bounds__(256) void out_kernel(
    const float* __restrict__ wo, const float* __restrict__ hidden,
    const float* __restrict__ ws, float* __restrict__ out)
{
    __shared__ float ctx[HIDDEN];
    const int t = threadIdx.x;
    ((float4*)ctx)[t * 2]     = ((const float4*)(ws + WS_CTX))[t * 2];
    ((float4*)ctx)[t * 2 + 1] = ((const float4*)(ws + WS_CTX))[t * 2 + 1];
    __syncthreads();

    const int lane = t & 63, wid = t >> 6;
    const int row0 = blockIdx.x * 8 + wid * 2;
    const float4* w04 = (const float4*)(wo + (size_t)row0 * HIDDEN);
    const float4* w14 = (const float4*)(wo + (size_t)(row0 + 1) * HIDDEN);
    const float4* c4 = (const float4*)ctx;
    float a0 = 0.f, a1 = 0.f;
    #pragma unroll
    for (int j = 0; j < 8; ++j) {
        float4 n = c4[j * 64 + lane];
        float4 u = w04[j * 64 + lane];
        float4 v = w14[j * 64 + lane];
        a0 += u.x*n.x + u.y*n.y + u.z*n.z + u.w*n.w;
        a1 += v.x*n.x + v.y*n.y + v.z*n.z + v.w*n.w;
    }
    #pragma unroll
    for (int m = 32; m; m >>= 1) { a0 += __shfl_xor(a0, m); a1 += __shfl_xor(a1, m); }
    if (lane == 0) {
        out[row0]     = hidden[row0]     + a0;
        out[row0 + 1] = hidden[row0 + 1] + a1;
    }
}

extern "C" void kernel_launch(void* const* d_in, const int* in_sizes, int n_in,
                              void* d_out, int out_size, void* d_ws, size_t ws_size,
                              hipStream_t stream)
{
    const float* hidden = (const float*)d_in[0];
    const int*   cur    = (const int*)d_in[3];
    const float* lnw    = (const float*)d_in[4];
    const float* wq     = (const float*)d_in[5];
    const float* bq     = (const float*)d_in[6];
    const float* wk     = (const float*)d_in[7];
    const float* bk     = (const float*)d_in[8];
    const float* wv     = (const float*)d_in[9];
    const float* bv     = (const float*)d_in[10];
    const float* wo     = (const float*)d_in[11];
    const float* kv     = (const float*)d_in[12];
    float* ws  = (float*)d_ws;
    float* out = (float*)d_out;

    qkv_kernel<<<dim3(320), dim3(256), 0, stream>>>(hidden, lnw, wq, bq, wk, bk, wv, bv, ws);
    attn_kernel<<<dim3(NPAIR * NCHUNKS), dim3(256), 0, stream>>>(kv, cur, ws);
    combine_kernel<<<dim3(NH), dim3(HD), 0, stream>>>(cur, ws);
    out_kernel<<<dim3(256), dim3(256), 0, stream>>>(wo, hidden, ws, out);
}

// Round 2
// 37.919 us; speedup vs baseline: 1.4150x; 1.4150x over previous
//
#include <hip/hip_runtime.h>
#include <hip/hip_bf16.h>
#include <math.h>

#define HIDDEN 2048
#define NH 16
#define NKV 2
#define HD 128
#define CTX 4096
#define NL 36
#define EPS 1e-6f

#define CHUNK 128
#define NCHUNKS (CTX / CHUNK)   /* 32 */
#define HPB 4                   /* Q heads per attn block */
#define NGRP (NH / HPB)         /* 4 */

/* ws layout (float offsets) */
#define WS_QRAW 0               /* 2048 */
#define WS_KRAW 2048            /* 256 */
#define WS_VRAW 2304            /* 256 */
#define WS_TAB  2560            /* cos[64], sin[64] */
#define WS_PML  2688            /* NH*NCHUNKS*2 = 1024 (m,l per head/chunk) */
#define WS_PACC 3712            /* NH*NCHUNKS*128 = 65536 */

#define RSQRT_HD 0.08838834764831845f  /* 1/sqrt(128) */

__device__ __forceinline__ float dot4(float4 a, float4 b) {
    return a.x*b.x + a.y*b.y + a.z*b.z + a.w*b.w;
}

// ---------------------------------------------------------------- K1: QKV
// blocks 0..319: 8 rows each of the fused [wq;wk;wv] matvec.
// block 320: RoPE cos/sin table (double angle + range-reduce, then sincosf).
__global__ __launch_bounds__(256) void qkv_kernel(
    const float* __restrict__ x, const float* __restrict__ lnw,
    const float* __restrict__ wq, const float* __restrict__ bq,
    const float* __restrict__ wk, const float* __restrict__ bk,
    const float* __restrict__ wv, const float* __restrict__ bv,
    const int* __restrict__ curpos, float* __restrict__ ws)
{
    const int t = threadIdx.x;
    const int lane = t & 63, wid = t >> 6;

    if (blockIdx.x == 320) {
        if (t < 64) {
            double e = (double)t * (1.0 / 64.0);
            double invf = exp2(-19.931568569324174087 * e);   /* 1e6^-e */
            double a = (double)curpos[0] * invf;
            a -= 6.2831853071795864769 * floor(a * 0.15915494309189533577);
            float s, c;
            sincosf((float)a, &s, &c);
            ws[WS_TAB + t] = c;
            ws[WS_TAB + 64 + t] = s;
        }
        return;
    }

    // ---- hoist weight loads (64 VGPRs) so the HBM stream starts immediately
    const int R0 = blockIdx.x * 8 + wid * 2;
    const float *w0, *w1; float b0, b1; float *dst0, *dst1;
    {
        int R = R0;
        if (R < 2048)      { w0 = wq + (size_t)R * HIDDEN;            b0 = bq[R];   dst0 = ws + WS_QRAW + R; }
        else if (R < 2304) { int r = R - 2048; w0 = wk + (size_t)r * HIDDEN; b0 = bk[r]; dst0 = ws + WS_KRAW + r; }
        else               { int r = R - 2304; w0 = wv + (size_t)r * HIDDEN; b0 = bv[r]; dst0 = ws + WS_VRAW + r; }
        R = R0 + 1;
        if (R < 2048)      { w1 = wq + (size_t)R * HIDDEN;            b1 = bq[R];   dst1 = ws + WS_QRAW + R; }
        else if (R < 2304) { int r = R - 2048; w1 = wk + (size_t)r * HIDDEN; b1 = bk[r]; dst1 = ws + WS_KRAW + r; }
        else               { int r = R - 2304; w1 = wv + (size_t)r * HIDDEN; b1 = bv[r]; dst1 = ws + WS_VRAW + r; }
    }
    const float4* w04 = (const float4*)w0;
    const float4* w14 = (const float4*)w1;
    float4 u[8], v[8];
    #pragma unroll
    for (int j = 0; j < 8; ++j) { u[j] = w04[j * 64 + lane]; v[j] = w14[j * 64 + lane]; }

    // ---- RMSNorm (redundant per block; x/lnw L2-resident)
    __shared__ float nx[HIDDEN];
    __shared__ float red[4];
    float4 xa = ((const float4*)x)[t * 2];
    float4 xb = ((const float4*)x)[t * 2 + 1];
    float ss = dot4(xa, xa) + dot4(xb, xb);
    #pragma unroll
    for (int m = 32; m; m >>= 1) ss += __shfl_xor(ss, m);
    if (lane == 0) red[wid] = ss;
    __syncthreads();
    float inv = rsqrtf((red[0] + red[1] + red[2] + red[3]) / (float)HIDDEN + EPS);
    float4 la = ((const float4*)lnw)[t * 2];
    float4 lb = ((const float4*)lnw)[t * 2 + 1];
    float4 na, nb;
    na.x = xa.x * inv * la.x; na.y = xa.y * inv * la.y;
    na.z = xa.z * inv * la.z; na.w = xa.w * inv * la.w;
    nb.x = xb.x * inv * lb.x; nb.y = xb.y * inv * lb.y;
    nb.z = xb.z * inv * lb.z; nb.w = xb.w * inv * lb.w;
    ((float4*)nx)[t * 2] = na;
    ((float4*)nx)[t * 2 + 1] = nb;
    __syncthreads();

    // ---- dot
    const float4* nx4 = (const float4*)nx;
    float a0 = 0.f, a1 = 0.f;
    #pragma unroll
    for (int j = 0; j < 8; ++j) {
        float4 n = nx4[j * 64 + lane];
        a0 += dot4(u[j], n);
        a1 += dot4(v[j], n);
    }
    #pragma unroll
    for (int m = 32; m; m >>= 1) { a0 += __shfl_xor(a0, m); a1 += __shfl_xor(a1, m); }
    if (lane == 0) { *dst0 = a0 + b0; *dst1 = a1 + b1; }
}

// ------------------------------------------------------- K2: attn partials
__global__ __launch_bounds__(256) void attn_kernel(
    const float* __restrict__ kv, const int* __restrict__ curpos,
    float* __restrict__ ws)
{
    const int pos = curpos[0];
    const int grp = blockIdx.x / NCHUNKS;
    const int c = blockIdx.x % NCHUNKS;
    const int start = c * CHUNK;
    if (start > pos) return;
    const int nvalid = min(CHUNK, pos + 1 - start);
    const int h0 = grp * HPB;
    const int kvh = h0 / (NH / NKV);
    const float* kc = kv + (size_t)kvh * CTX * HD;
    const float* vc = kv + (size_t)(NL * NKV + kvh) * CTX * HD;

    __shared__ float tab[128];
    __shared__ float qr[HPB][HD];
    __shared__ float sc[HPB][CHUNK];
    __shared__ float ctxh[8][HPB][HD];

    const int t = threadIdx.x;
    const int lane = t & 63, wid = t >> 6;

    if (t < 128) tab[t] = ws[WS_TAB + t];
    __syncthreads();

    // q RoPE + scale: 512 elems, 2 per thread
    #pragma unroll
    for (int i = 0; i < 2; ++i) {
        int e = t + i * 256;
        int hh = e >> 7, d = e & 127;
        const float* q = ws + WS_QRAW + (size_t)(h0 + hh) * HD;
        float qv = q[d], qp = q[d ^ 64];
        float r = (d < 64) ? -qp : qp;
        qr[hh][d] = (qv * tab[d & 63] + r * tab[64 + (d & 63)]) * RSQRT_HD;
    }
    __syncthreads();

    // scores: 16 groups of 16 lanes; q fragments preloaded to registers
    const int g16 = t >> 4, li = t & 15;
    float qreg[HPB][8];
    #pragma unroll
    for (int h = 0; h < HPB; ++h)
        #pragma unroll
        for (int j = 0; j < 8; ++j) qreg[h][j] = qr[h][li * 8 + j];

    for (int base = 0; base < nvalid; base += 16) {
        const int pl = base + g16;
        float s0 = 0.f, s1 = 0.f, s2 = 0.f, s3 = 0.f;
        if (pl < nvalid) {
            const int p = start + pl;
            float kd[8];
            if (p == pos) {  // fresh k, roped on the fly
                const float* kr = ws + WS_KRAW + (size_t)kvh * HD;
                #pragma unroll
                for (int j = 0; j < 8; ++j) {
                    int d = li * 8 + j;
                    float kvd = kr[d], kp = kr[d ^ 64];
                    float r = (d < 64) ? -kp : kp;
                    kd[j] = kvd * tab[d & 63] + r * tab[64 + (d & 63)];
                }
            } else {
                const float4* kp4 = (const float4*)(kc + (size_t)p * HD + li * 8);
                float4 ka = kp4[0], kb = kp4[1];
                kd[0]=ka.x; kd[1]=ka.y; kd[2]=ka.z; kd[3]=ka.w;
                kd[4]=kb.x; kd[5]=kb.y; kd[6]=kb.z; kd[7]=kb.w;
            }
            #pragma unroll
            for (int j = 0; j < 8; ++j) {
                s0 += qreg[0][j] * kd[j];
                s1 += qreg[1][j] * kd[j];
                s2 += qreg[2][j] * kd[j];
                s3 += qreg[3][j] * kd[j];
            }
        }
        #pragma unroll
        for (int m = 1; m < 16; m <<= 1) {
            s0 += __shfl_xor(s0, m); s1 += __shfl_xor(s1, m);
            s2 += __shfl_xor(s2, m); s3 += __shfl_xor(s3, m);
        }
        if (pl < nvalid && li == 0) { sc[0][pl] = s0; sc[1][pl] = s1; sc[2][pl] = s2; sc[3][pl] = s3; }
    }
    __syncthreads();

    // softmax stats: wave w -> head w
    {
        float m = -INFINITY;
        for (int p = lane; p < nvalid; p += 64) m = fmaxf(m, sc[wid][p]);
        #pragma unroll
        for (int mm = 32; mm; mm >>= 1) m = fmaxf(m, __shfl_xor(m, mm));
        float l = 0.f;
        for (int p = lane; p < nvalid; p += 64) {
            float e = expf(sc[wid][p] - m);
            sc[wid][p] = e;
            l += e;
        }
        #pragma unroll
        for (int mm = 32; mm; mm >>= 1) l += __shfl_xor(l, mm);
        if (lane == 0) {
            ws[WS_PML + ((size_t)(h0 + wid) * NCHUNKS + c) * 2]     = m;
            ws[WS_PML + ((size_t)(h0 + wid) * NCHUNKS + c) * 2 + 1] = l;
        }
    }
    __syncthreads();

    // ctx partial: float4 over dims, 8 position streams, v amortized x4 heads
    {
        const int q4 = t & 31, half = t >> 5;
        float4 a[HPB];
        #pragma unroll
        for (int h = 0; h < HPB; ++h) a[h] = make_float4(0.f, 0.f, 0.f, 0.f);
        for (int pl = half; pl < nvalid; pl += 8) {
            const int p = start + pl;
            const float4* vp = (p == pos) ? (const float4*)(ws + WS_VRAW + (size_t)kvh * HD)
                                          : (const float4*)(vc + (size_t)p * HD);
            float4 vv = vp[q4];
            #pragma unroll
            for (int h = 0; h < HPB; ++h) {
                float w = sc[h][pl];
                a[h].x += w * vv.x; a[h].y += w * vv.y;
                a[h].z += w * vv.z; a[h].w += w * vv.w;
            }
        }
        #pragma unroll
        for (int h = 0; h < HPB; ++h)
            *(float4*)&ctxh[half][h][q4 * 4] = a[h];
    }
    __syncthreads();

    #pragma unroll
    for (int i = 0; i < 2; ++i) {
        int e = t + i * 256;
        int hh = e >> 7, d = e & 127;
        float s = 0.f;
        #pragma unroll
        for (int hf = 0; hf < 8; ++hf) s += ctxh[hf][hh][d];
        ws[WS_PACC + ((size_t)(h0 + hh) * NCHUNKS + c) * 128 + d] = s;
    }
}

// --------------------------------------- K3: combine + out proj + residual
__global__ __launch_bounds__(256) void out_kernel(
    const float* __restrict__ wo, const float* __restrict__ hidden,
    const float* __restrict__ ws, const int* __restrict__ curpos,
    float* __restrict__ out)
{
    const int t = threadIdx.x;
    const int lane = t & 63, wid = t >> 6;

    // hoist weight loads so the 16MB stream is in flight during combine
    const int row0 = blockIdx.x * 8 + wid * 2;
    const float4* w04 = (const float4*)(wo + (size_t)row0 * HIDDEN);
    const float4* w14 = (const float4*)(wo + (size_t)(row0 + 1) * HIDDEN);
    float4 u[8], v[8];
    #pragma unroll
    for (int j = 0; j < 8; ++j) { u[j] = w04[j * 64 + lane]; v[j] = w14[j * 64 + lane]; }

    // redundant per-block combine: thread -> head t>>4, dims (t&15)*8..+7
    __shared__ float ctx[HIDDEN];
    const int pos = curpos[0];
    const int nc = pos / CHUNK + 1;
    const int h = t >> 4, sub = t & 15;
    float M = -INFINITY;
    for (int c = 0; c < nc; ++c)
        M = fmaxf(M, ws[WS_PML + ((size_t)h * NCHUNKS + c) * 2]);
    float L = 0.f;
    float4 acc0 = make_float4(0.f,0.f,0.f,0.f), acc1 = make_float4(0.f,0.f,0.f,0.f);
    for (int c = 0; c < nc; ++c) {
        float mm = ws[WS_PML + ((size_t)h * NCHUNKS + c) * 2];
        float ll = ws[WS_PML + ((size_t)h * NCHUNKS + c) * 2 + 1];
        float w = expf(mm - M);
        L += w * ll;
        const float4* pa = (const float4*)(ws + WS_PACC + ((size_t)h * NCHUNKS + c) * 128 + sub * 8);
        float4 p0 = pa[0], p1 = pa[1];
        acc0.x += w*p0.x; acc0.y += w*p0.y; acc0.z += w*p0.z; acc0.w += w*p0.w;
        acc1.x += w*p1.x; acc1.y += w*p1.y; acc1.z += w*p1.z; acc1.w += w*p1.w;
    }
    float invL = 1.f / L;
    acc0.x *= invL; acc0.y *= invL; acc0.z *= invL; acc0.w *= invL;
    acc1.x *= invL; acc1.y *= invL; acc1.z *= invL; acc1.w *= invL;
    *(float4*)&ctx[h * HD + sub * 8]     = acc0;
    *(float4*)&ctx[h * HD + sub * 8 + 4] = acc1;
    __syncthreads();

    const float4* c4 = (const float4*)ctx;
    float a0 = 0.f, a1 = 0.f;
    #pragma unroll
    for (int j = 0; j < 8; ++j) {
        float4 n = c4[j * 64 + lane];
        a0 += dot4(u[j], n);
        a1 += dot4(v[j], n);
    }
    #pragma unroll
    for (int m = 32; m; m >>= 1) { a0 += __shfl_xor(a0, m); a1 += __shfl_xor(a1, m); }
    if (lane == 0) {
        out[row0]     = hidden[row0]     + a0;
        out[row0 + 1] = hidden[row0 + 1] + a1;
    }
}

extern "C" void kernel_launch(void* const* d_in, const int* in_sizes, int n_in,
                              void* d_out, int out_size, void* d_ws, size_t ws_size,
                              hipStream_t stream)
{
    const float* hidden = (const float*)d_in[0];
    const int*   cur    = (const int*)d_in[3];
    const float* lnw    = (const float*)d_in[4];
    const float* wq     = (const float*)d_in[5];
    const float* bq     = (const float*)d_in[6];
    const float* wk     = (const float*)d_in[7];
    const float* bk     = (const float*)d_in[8];
    const float* wv     = (const float*)d_in[9];
    const float* bv     = (const float*)d_in[10];
    const float* wo     = (const float*)d_in[11];
    const float* kv     = (const float*)d_in[12];
    float* ws  = (float*)d_ws;
    float* out = (float*)d_out;

    qkv_kernel<<<dim3(321), dim3(256), 0, stream>>>(hidden, lnw, wq, bq, wk, bk, wv, bv, cur, ws);
    attn_kernel<<<dim3(NGRP * NCHUNKS), dim3(256), 0, stream>>>(kv, cur, ws);
    out_kernel<<<dim3(256), dim3(256), 0, stream>>>(wo, hidden, ws, cur, out);
}